// Round 10
// baseline (708.654 us; speedup 1.0000x reference)
//
#include <hip/hip_runtime.h>
#include <hip/hip_fp16.h>

typedef __half h16;
static __device__ __forceinline__ h16  f2h(float v){ return __float2half(v); }

typedef _Float16 f16x8 __attribute__((ext_vector_type(8)));
typedef float    f32x4 __attribute__((ext_vector_type(4)));

// pack two floats -> h2 in a uint (RNE)
static __device__ __forceinline__ unsigned pk2(float a, float b){
  return ((unsigned)__half_as_ushort(__float2half(b)) << 16) |
          (unsigned)__half_as_ushort(__float2half(a));
}

#define HEADS 8
#define HID 32
#define NHID 256

// ---------------- CSR build + weight packing ----------------
// fused: edge-degree count (idx<E) + all MFMA weight fragment packing (idx<117760)
__global__ void k_count_pack(const int* __restrict__ ei, int* __restrict__ deg, int E,
                             const float* __restrict__ W1, const float* __restrict__ W2,
                             const float* __restrict__ Wp1, const float* __restrict__ Wm1,
                             const float* __restrict__ Wm2,
                             _Float16* __restrict__ Wpk1, _Float16* __restrict__ Wpk2,
                             _Float16* __restrict__ Wpkp, _Float16* __restrict__ Apke){
  int idx = blockIdx.x*256 + threadIdx.x;
  if (idx < E) atomicAdd(&deg[ei[E + idx]], 1);   // dst = edge_index[1]
  if (idx < 32768){
    int i = idx;
    int j=i&7, lane=(i>>3)&63, ct=(i>>9)&15, kc=i>>13;
    int k = kc*32 + ((lane>>4)<<3) + j, c = (ct<<4) + (lane&15);
    Wpk1[i] = (_Float16)W1[(size_t)k*NHID + c];
  } else if (idx < 98304){
    int i = idx - 32768;
    int j=i&7, lane=(i>>3)&63, ct=(i>>9)&15, kc=i>>13;
    int k = kc*32 + ((lane>>4)<<3) + j, c = (ct<<4) + (lane&15);
    Wpk2[i] = (_Float16)W2[(size_t)k*NHID + c];
  } else if (idx < 114688){
    int i = idx - 98304;
    int j=i&7, lane=(i>>3)&63, ct=(i>>9)&3, kc=i>>11;
    int k = kc*32 + ((lane>>4)<<3) + j, c = (ct<<4) + (lane&15);
    float v = (c < 32) ? Wp1[(size_t)k*32 + c] : Wp1[(size_t)(256+k)*32 + (c-32)];
    Wpkp[i] = (_Float16)v;
  } else if (idx < 117760){
    int i = idx - 114688;               // < 3072
    int j=i&7, lane=(i>>3)&63, mt=(i>>9)&1, layer=i>>10;
    int k = ((lane>>4)<<3) + j, c = mt*16 + (lane&15);
    const float* W = (layer==0) ? Wm1 : (layer==1) ? Wm2 : (Wp1 + 512*32);
    Apke[i] = (_Float16)W[k*32 + c];
  }
}
__global__ void k_scan_part(const int* __restrict__ deg, int* __restrict__ bsum, int N){
  __shared__ int s[256];
  int t = threadIdx.x, i = blockIdx.x*256 + t;
  s[t] = (i < N) ? deg[i] + 1 : 0;
  __syncthreads();
  for (int off = 128; off > 0; off >>= 1){
    if (t < off) s[t] += s[t+off];
    __syncthreads();
  }
  if (t == 0) bsum[blockIdx.x] = s[0];
}
__global__ void k_scan_top(const int* __restrict__ bsum, int* __restrict__ bpre, int nb){
  __shared__ int s[256];
  int t = threadIdx.x;
  int v = (t < nb) ? bsum[t] : 0;
  s[t] = v; __syncthreads();
  for (int off = 1; off < 256; off <<= 1){
    int x = (t >= off) ? s[t-off] : 0;
    __syncthreads();
    s[t] += x;
    __syncthreads();
  }
  if (t < nb) bpre[t] = s[t] - v;             // exclusive block prefix
}
// fills row_start + self-loop entry + cursor + degree-bucket counts
__global__ void k_scan_final(const int* __restrict__ deg, const int* __restrict__ bpre,
                             int* __restrict__ row_start, int* __restrict__ csr_src,
                             int* __restrict__ cursor, int* __restrict__ bcnt,
                             int N, int total){
  __shared__ int s[256];
  int t = threadIdx.x, i = blockIdx.x*256 + t;
  int v = (i < N) ? deg[i] + 1 : 0;
  s[t] = v; __syncthreads();
  for (int off = 1; off < 256; off <<= 1){
    int x = (t >= off) ? s[t-off] : 0;
    __syncthreads();
    s[t] += x;
    __syncthreads();
  }
  if (i < N){
    int p = bpre[blockIdx.x] + s[t] - v;
    row_start[i] = p;
    csr_src[p] = i;          // self-loop first
    cursor[i] = p + 1;
    atomicAdd(&bcnt[min(v, 31)], 1);
  }
  if (i == 0) row_start[N] = total;
}
__global__ void k_bucket_scan(const int* __restrict__ bcnt, int* __restrict__ boff){
  if (threadIdx.x == 0){
    int run = 0;
    for (int b = 0; b < 32; b++){ boff[b] = run; run += bcnt[b]; }
  }
}
__global__ void k_bucket_scatter(const int* __restrict__ deg, int* __restrict__ boff,
                                 int* __restrict__ order, int N){
  int n = blockIdx.x*256 + threadIdx.x;
  if (n < N){
    int b = min(deg[n] + 1, 31);
    int pos = atomicAdd(&boff[b], 1);
    order[pos] = n;
  }
}
__global__ void k_fill_edges(const int* __restrict__ ei, int* __restrict__ cursor,
                             int* __restrict__ csr_src, int E){
  int e = blockIdx.x*256 + threadIdx.x;
  if (e < E){
    int src = ei[e], dst = ei[E + e];
    int p = atomicAdd(&cursor[dst], 1);
    csr_src[p] = src;
  }
}

// ---------------- MFMA GEMM (X@W) + alpha; H/AS/AD written HEAD-MAJOR ----------------
// H: [8][N][32] fp16; AS/AD: [8][N] fp32. INF32=false input X is head-major [8][N][32] h16.
template<int K, bool INF32>
__global__ __launch_bounds__(256) void k_gemm_mfma(
    const void* __restrict__ xin, const _Float16* __restrict__ Wpk,
    const float* __restrict__ asrc, const float* __restrict__ adst,
    h16* __restrict__ H, float* __restrict__ AS, float* __restrict__ AD, int N)
{
  __shared__ __align__(16) _Float16 xs[32][K+8];   // +8 halves pad
  const int t = threadIdx.x;
  const int n0 = blockIdx.x * 32;
  constexpr int K8 = K/8;
  for (int i = t; i < 32*K8; i += 256){
    int r = i / K8, c8 = (i - r*K8)*8;
    if (INF32){
      _Float16 v[8];
      if (n0+r < N){
        const float4* gp = (const float4*)((const float*)xin + (size_t)(n0+r)*K + c8);
        float4 u0 = gp[0], u1 = gp[1];
        v[0]=(_Float16)u0.x; v[1]=(_Float16)u0.y; v[2]=(_Float16)u0.z; v[3]=(_Float16)u0.w;
        v[4]=(_Float16)u1.x; v[5]=(_Float16)u1.y; v[6]=(_Float16)u1.z; v[7]=(_Float16)u1.w;
      } else {
        for (int j=0;j<8;j++) v[j]=(_Float16)0.f;
      }
      *(f16x8*)&xs[r][c8] = *(f16x8*)v;
    } else {
      uint4 u = make_uint4(0,0,0,0);
      if (n0+r < N)
        u = *(const uint4*)((const h16*)xin + ((size_t)(c8>>5)*N + (n0+r))*32 + (c8&31));
      *(uint4*)&xs[r][c8] = u;
    }
  }
  __syncthreads();

  const int wid = t >> 6, lane = t & 63;
  const int mcol = lane & 15, kq = lane >> 4;
  f32x4 acc[4][2];
#pragma unroll
  for (int ct = 0; ct < 4; ct++)
#pragma unroll
    for (int rt = 0; rt < 2; rt++) acc[ct][rt] = (f32x4){0.f,0.f,0.f,0.f};

  for (int kc = 0; kc < K/32; kc++){
    f16x8 a0 = *(const f16x8*)&xs[mcol     ][kc*32 + kq*8];
    f16x8 a1 = *(const f16x8*)&xs[16 + mcol][kc*32 + kq*8];
#pragma unroll
    for (int ct = 0; ct < 4; ct++){
      f16x8 b = *(const f16x8*)&Wpk[(((size_t)kc*16 + wid*4 + ct)*64 + lane)*8];
      acc[ct][0] = __builtin_amdgcn_mfma_f32_16x16x32_f16(a0, b, acc[ct][0], 0,0,0);
      acc[ct][1] = __builtin_amdgcn_mfma_f32_16x16x32_f16(a1, b, acc[ct][1], 0,0,0);
    }
  }

  float av[4], dv[4];
#pragma unroll
  for (int ct = 0; ct < 4; ct++){
    int c = wid*64 + ct*16 + mcol;
    av[ct] = asrc[c]; dv[ct] = adst[c];
  }
#pragma unroll
  for (int rt = 0; rt < 2; rt++){
#pragma unroll
    for (int r = 0; r < 4; r++){
      const int n = n0 + rt*16 + kq*4 + r;
      const bool ok = n < N;
      if (ok){
#pragma unroll
        for (int ct = 0; ct < 4; ct++){
          H[((size_t)(wid*2 + (ct>>1))*N + n)*32 + (ct&1)*16 + mcol] = f2h(acc[ct][rt][r]);
        }
      }
      float s1a = acc[0][rt][r]*av[0] + acc[1][rt][r]*av[1];
      float s2a = acc[0][rt][r]*dv[0] + acc[1][rt][r]*dv[1];
      float s1b = acc[2][rt][r]*av[2] + acc[3][rt][r]*av[3];
      float s2b = acc[2][rt][r]*dv[2] + acc[3][rt][r]*dv[3];
#pragma unroll
      for (int off = 1; off < 16; off <<= 1){
        s1a += __shfl_xor(s1a, off); s2a += __shfl_xor(s2a, off);
        s1b += __shfl_xor(s1b, off); s2b += __shfl_xor(s2b, off);
      }
      if (mcol == 0 && ok){
        AS[(size_t)(wid*2    )*N + n] = s1a;  AD[(size_t)(wid*2    )*N + n] = s2a;
        AS[(size_t)(wid*2 + 1)*N + n] = s1b;  AD[(size_t)(wid*2 + 1)*N + n] = s2b;
      }
    }
  }
}

// ------------- GAT aggregation: 4-lane group per (node, head), head-split + XCD swizzle ----
// Nodes taken in degree-bucketed order -> waves have near-uniform degree (minimal masked
// iterations). Unroll-4: 4 gather chains in flight, 2 FMA accumulation chains.
__global__ __launch_bounds__(256) void k_gat_agg(
    const int* __restrict__ row_start, const int* __restrict__ csr_src,
    const int* __restrict__ order,
    const h16* __restrict__ H, const float* __restrict__ AS, const float* __restrict__ AD,
    const float* __restrict__ bias, h16* __restrict__ Xout, int N)
{
  const int head = blockIdx.x & 7;
  const int t = threadIdx.x;
  const int wv = t >> 6, lane = t & 63;
  const int g = lane >> 2, cl = lane & 3;
  const int ni = (blockIdx.x >> 3)*64 + wv*16 + g;
  if (ni >= N) return;
  const int n = order[ni];
  const int rs = row_start[n];
  const int deg = row_start[n+1] - rs;         // >=1 (self-loop)
  const h16* __restrict__ Hh = H + (size_t)head*N*32;
  const float* __restrict__ ASh = AS + (size_t)head*N;
  const float adv = AD[(size_t)head*N + n];
  const int co = cl*8;

  float accA[8] = {0,0,0,0,0,0,0,0};
  float accB[8] = {0,0,0,0,0,0,0,0};
  float dA = 0.f, dB = 0.f;
  int k = 0;
  for (; k + 4 <= deg; k += 4){
    const int s0 = csr_src[rs + k    ];
    const int s1 = csr_src[rs + k + 1];
    const int s2 = csr_src[rs + k + 2];
    const int s3 = csr_src[rs + k + 3];
    const float v0 = ASh[s0] + adv;
    const float v1 = ASh[s1] + adv;
    const float v2 = ASh[s2] + adv;
    const float v3 = ASh[s3] + adv;
    union { uint4 u; __half2 h[4]; } h0, h1, h2, h3;
    h0.u = *(const uint4*)(Hh + (size_t)s0*32 + co);
    h1.u = *(const uint4*)(Hh + (size_t)s1*32 + co);
    h2.u = *(const uint4*)(Hh + (size_t)s2*32 + co);
    h3.u = *(const uint4*)(Hh + (size_t)s3*32 + co);
    const float w0 = __expf(v0 > 0.f ? v0 : 0.2f*v0);
    const float w1 = __expf(v1 > 0.f ? v1 : 0.2f*v1);
    const float w2 = __expf(v2 > 0.f ? v2 : 0.2f*v2);
    const float w3 = __expf(v3 > 0.f ? v3 : 0.2f*v3);
    dA += w0 + w2; dB += w1 + w3;
#pragma unroll
    for (int i = 0; i < 4; i++){
      float2 f0 = __half22float2(h0.h[i]);
      float2 f1 = __half22float2(h1.h[i]);
      float2 f2 = __half22float2(h2.h[i]);
      float2 f3 = __half22float2(h3.h[i]);
      accA[2*i]   = fmaf(w0, f0.x, fmaf(w2, f2.x, accA[2*i]));
      accA[2*i+1] = fmaf(w0, f0.y, fmaf(w2, f2.y, accA[2*i+1]));
      accB[2*i]   = fmaf(w1, f1.x, fmaf(w3, f3.x, accB[2*i]));
      accB[2*i+1] = fmaf(w1, f1.y, fmaf(w3, f3.y, accB[2*i+1]));
    }
  }
  for (; k < deg; k++){
    const int sa = csr_src[rs + k];
    const float va = ASh[sa] + adv;
    union { uint4 u; __half2 h[4]; } ha;
    ha.u = *(const uint4*)(Hh + (size_t)sa*32 + co);
    const float wa = __expf(va > 0.f ? va : 0.2f*va);
    dA += wa;
#pragma unroll
    for (int i = 0; i < 4; i++){
      float2 fa = __half22float2(ha.h[i]);
      accA[2*i]   = fmaf(wa, fa.x, accA[2*i]);
      accA[2*i+1] = fmaf(wa, fa.y, accA[2*i+1]);
    }
  }
  const float inv_d = 1.f / (dA + dB);
  const float4 b0 = *(const float4*)(bias + head*32 + co);
  const float4 b1 = *(const float4*)(bias + head*32 + co + 4);
  uint4 o;
  o.x = pk2(fmaxf(fmaf(accA[0]+accB[0], inv_d, b0.x), 0.f),
            fmaxf(fmaf(accA[1]+accB[1], inv_d, b0.y), 0.f));
  o.y = pk2(fmaxf(fmaf(accA[2]+accB[2], inv_d, b0.z), 0.f),
            fmaxf(fmaf(accA[3]+accB[3], inv_d, b0.w), 0.f));
  o.z = pk2(fmaxf(fmaf(accA[4]+accB[4], inv_d, b1.x), 0.f),
            fmaxf(fmaf(accA[5]+accB[5], inv_d, b1.y), 0.f));
  o.w = pk2(fmaxf(fmaf(accA[6]+accB[6], inv_d, b1.z), 0.f),
            fmaxf(fmaf(accA[7]+accB[7], inv_d, b1.w), 0.f));
  *(uint4*)(Xout + ((size_t)head*N + n)*32 + co) = o;
}

// ------------- MFMA node projections: P[N][64] = X2(head-major) @ Wcat -------------
__global__ __launch_bounds__(256) void k_node_proj_mfma(
    const h16* __restrict__ X2, const _Float16* __restrict__ Wpk,
    h16* __restrict__ P, int N)
{
  __shared__ __align__(16) _Float16 xs[64][NHID+8];
  const int t = threadIdx.x;
  const int n0 = blockIdx.x * 64;
  for (int i = t; i < 64*32; i += 256){
    int r = i >> 5, c8 = (i & 31)*8;
    uint4 u = make_uint4(0,0,0,0);
    if (n0+r < N)
      u = *(const uint4*)(X2 + ((size_t)(c8>>5)*N + (n0+r))*32 + (c8&31));
    *(uint4*)&xs[r][c8] = u;
  }
  __syncthreads();

  const int wid = t >> 6, lane = t & 63;
  const int mcol = lane & 15, kq = lane >> 4;
  f32x4 acc[4];
#pragma unroll
  for (int rt = 0; rt < 4; rt++) acc[rt] = (f32x4){0.f,0.f,0.f,0.f};

  for (int kc = 0; kc < 8; kc++){
    f16x8 b = *(const f16x8*)&Wpk[(((size_t)kc*4 + wid)*64 + lane)*8];
#pragma unroll
    for (int rt = 0; rt < 4; rt++){
      f16x8 a = *(const f16x8*)&xs[rt*16 + mcol][kc*32 + kq*8];
      acc[rt] = __builtin_amdgcn_mfma_f32_16x16x32_f16(a, b, acc[rt], 0,0,0);
    }
  }

  const int c = wid*16 + mcol;
#pragma unroll
  for (int rt = 0; rt < 4; rt++){
#pragma unroll
    for (int r = 0; r < 4; r++){
      const int n = n0 + rt*16 + kq*4 + r;
      if (n < N) P[(size_t)n*64 + c] = f2h(acc[rt][r]);
    }
  }
}

// ------------- edge tail, all-register MFMA: zero LDS, zero barriers -------------
__global__ __launch_bounds__(256) void k_edge_mfma(
    const int* __restrict__ ei, const float* __restrict__ ea,
    const _Float16* __restrict__ Apk,
    const float* __restrict__ bm1, const float* __restrict__ bm2,
    const float* __restrict__ bp1,
    const h16* __restrict__ P, const float* __restrict__ Wp2,
    const float* __restrict__ bp2,
    float* __restrict__ out, int E)
{
  union U8 { f16x8 v; unsigned u[4]; };
  const int t = threadIdx.x;
  const int wid = t >> 6, lane = t & 63;
  const int mcol = lane & 15, kq = lane >> 4;
  const int e0w = blockIdx.x*256 + wid*64;

  float4 bv1[2], bv2[2], bv3[2], wv4[2];
#pragma unroll
  for (int mt = 0; mt < 2; mt++){
    bv1[mt] = *(const float4*)(bm1 + mt*16 + kq*4);
    bv2[mt] = *(const float4*)(bm2 + mt*16 + kq*4);
    bv3[mt] = *(const float4*)(bp1 + mt*16 + kq*4);
    wv4[mt] = *(const float4*)(Wp2 + mt*16 + kq*4);
  }
  const float bp2v = bp2[0];

  f32x4 acc[2][4];
  unsigned pkLo[2][4], pkHi[2][4];
  const int l1 = (kq & 1)*32 + mcol;
  const int l2 = l1 + 16;
  const int mt_hi = kq >> 1;

  // ---- layer 1: B from global ea ----
#pragma unroll
  for (int nt = 0; nt < 4; nt++){
    const int e = e0w + nt*16 + mcol;
    U8 b;
    if (e < E){
      const float4* gp = (const float4*)(ea + (size_t)e*32 + kq*8);
      float4 u0 = gp[0], u1 = gp[1];
      b.u[0] = pk2(u0.x, u0.y); b.u[1] = pk2(u0.z, u0.w);
      b.u[2] = pk2(u1.x, u1.y); b.u[3] = pk2(u1.z, u1.w);
    } else {
      b.u[0]=b.u[1]=b.u[2]=b.u[3]=0u;
    }
#pragma unroll
    for (int mt = 0; mt < 2; mt++){
      f16x8 a = *(const f16x8*)&Apk[((0*2+mt)*64 + lane)*8];
      acc[mt][nt] = (f32x4){bv1[mt].x, bv1[mt].y, bv1[mt].z, bv1[mt].w};
      acc[mt][nt] = __builtin_amdgcn_mfma_f32_16x16x32_f16(a, b.v, acc[mt][nt], 0,0,0);
    }
  }

  // ---- transitions + layers 2,3 ----
#pragma unroll
  for (int layer = 1; layer < 3; layer++){
#pragma unroll
    for (int mt = 0; mt < 2; mt++)
#pragma unroll
      for (int nt = 0; nt < 4; nt++){
        float r0 = fmaxf(acc[mt][nt][0], 0.f), r1 = fmaxf(acc[mt][nt][1], 0.f);
        float r2 = fmaxf(acc[mt][nt][2], 0.f), r3 = fmaxf(acc[mt][nt][3], 0.f);
        pkLo[mt][nt] = pk2(r0, r1);
        pkHi[mt][nt] = pk2(r2, r3);
      }
#pragma unroll
    for (int nt = 0; nt < 4; nt++){
      unsigned a0 = (unsigned)__shfl((int)pkLo[0][nt], l1);
      unsigned a1 = (unsigned)__shfl((int)pkHi[0][nt], l1);
      unsigned a2 = (unsigned)__shfl((int)pkLo[0][nt], l2);
      unsigned a3 = (unsigned)__shfl((int)pkHi[0][nt], l2);
      unsigned c0 = (unsigned)__shfl((int)pkLo[1][nt], l1);
      unsigned c1 = (unsigned)__shfl((int)pkHi[1][nt], l1);
      unsigned c2 = (unsigned)__shfl((int)pkLo[1][nt], l2);
      unsigned c3 = (unsigned)__shfl((int)pkHi[1][nt], l2);
      U8 b;
      b.u[0] = mt_hi ? c0 : a0; b.u[1] = mt_hi ? c1 : a1;
      b.u[2] = mt_hi ? c2 : a2; b.u[3] = mt_hi ? c3 : a3;
      const float4 bv = (layer==1) ? bv2[0] : bv3[0];
      const float4 bw = (layer==1) ? bv2[1] : bv3[1];
      f16x8 A0 = *(const f16x8*)&Apk[((layer*2+0)*64 + lane)*8];
      f16x8 A1 = *(const f16x8*)&Apk[((layer*2+1)*64 + lane)*8];
      f32x4 n0 = (f32x4){bv.x, bv.y, bv.z, bv.w};
      f32x4 n1 = (f32x4){bw.x, bw.y, bw.z, bw.w};
      n0 = __builtin_amdgcn_mfma_f32_16x16x32_f16(A0, b.v, n0, 0,0,0);
      n1 = __builtin_amdgcn_mfma_f32_16x16x32_f16(A1, b.v, n1, 0,0,0);
      acc[0][nt] = n0;
      acc[1][nt] = n1;
    }
  }

  // ---- tail: p = sum_c relu(P1[row][c]+P2[col][c]+EC[e][c]) * Wp2[c] ----
#pragma unroll
  for (int nt = 0; nt < 4; nt++){
    const int e = e0w + nt*16 + mcol;
    const bool ok = e < E;
    const int row  = ok ? ei[e]     : 0;
    const int colv = ok ? ei[E + e] : 0;
    float p = 0.f;
#pragma unroll
    for (int mt = 0; mt < 2; mt++){
      const __half2* p1p = (const __half2*)(P + (size_t)row*64      + mt*16 + kq*4);
      const __half2* p2p = (const __half2*)(P + (size_t)colv*64 + 32 + mt*16 + kq*4);
      __half2 x0 = p1p[0], x1 = p1p[1], y0 = p2p[0], y1 = p2p[1];
      float v0 = __half2float(x0.x) + __half2float(y0.x) + acc[mt][nt][0];
      float v1 = __half2float(x0.y) + __half2float(y0.y) + acc[mt][nt][1];
      float v2 = __half2float(x1.x) + __half2float(y1.x) + acc[mt][nt][2];
      float v3 = __half2float(x1.y) + __half2float(y1.y) + acc[mt][nt][3];
      v0 = fmaxf(v0,0.f); v1 = fmaxf(v1,0.f); v2 = fmaxf(v2,0.f); v3 = fmaxf(v3,0.f);
      p += v0*wv4[mt].x + v1*wv4[mt].y + v2*wv4[mt].z + v3*wv4[mt].w;
    }
    p += __shfl_xor(p, 16);
    p += __shfl_xor(p, 32);
    if (kq == 0 && ok) out[e] = p + bp2v;
  }
}

extern "C" void kernel_launch(void* const* d_in, const int* in_sizes, int n_in,
                              void* d_out, int out_size, void* d_ws, size_t ws_size,
                              hipStream_t stream)
{
  const float* x   = (const float*)d_in[0];
  const int*   ei  = (const int*)  d_in[1];
  const float* ea  = (const float*)d_in[2];
  const float* W1  = (const float*)d_in[3];
  const float* as1 = (const float*)d_in[4];
  const float* ad1 = (const float*)d_in[5];
  const float* b1  = (const float*)d_in[6];
  const float* W2  = (const float*)d_in[7];
  const float* as2 = (const float*)d_in[8];
  const float* ad2 = (const float*)d_in[9];
  const float* b2  = (const float*)d_in[10];
  const float* Wm1 = (const float*)d_in[11];
  const float* bm1 = (const float*)d_in[12];
  const float* Wm2 = (const float*)d_in[13];
  const float* bm2 = (const float*)d_in[14];
  const float* Wp1 = (const float*)d_in[15];
  const float* bp1 = (const float*)d_in[16];
  const float* Wp2 = (const float*)d_in[17];
  const float* bp2 = (const float*)d_in[18];

  const int N = in_sizes[0] / 128;    // 50000
  const int E = in_sizes[1] / 2;      // 400000

  char* p = (char*)d_ws;
  auto carve = [&](size_t bytes) -> void* {
    void* q = (void*)p; p += (bytes + 255) & ~size_t(255); return q;
  };
  h16* Hh   = (h16*)carve((size_t)N*NHID*2);      // 25.6 MB [8][N][32]
  h16* Xh   = (h16*)carve((size_t)N*NHID*2);      // 25.6 MB [8][N][32] (X1 then X2)
  float* AS = (float*)carve((size_t)N*HEADS*4);   // 1.6 MB [8][N]
  float* AD = (float*)carve((size_t)N*HEADS*4);   // 1.6 MB [8][N]
  h16* P    = (h16*)carve((size_t)N*64*2);        // 6.4 MB  [N][64] = [P1|P2]
  int* deg       = (int*)carve((size_t)N*4);      // \  contiguous: one memset covers
  int* bcnt      = (int*)carve(128);              //  | deg + bcnt + boff
  int* boff      = (int*)carve(128);              // /
  int* cursor    = (int*)carve((size_t)N*4);
  int* row_start = (int*)carve((size_t)(N+1)*4);
  int* csr_src   = (int*)carve((size_t)(E+N)*4);
  int* order     = (int*)carve((size_t)N*4);
  int* bsum      = (int*)carve(1024);
  int* bpre      = (int*)carve(1024);
  _Float16* Wpk1 = (_Float16*)carve((size_t)128*NHID*2);  // 64 KB
  _Float16* Wpk2 = (_Float16*)carve((size_t)256*NHID*2);  // 128 KB
  _Float16* Wpkp = (_Float16*)carve((size_t)256*64*2);    // 32 KB
  _Float16* Apke = (_Float16*)carve((size_t)3072*2);      // 6 KB

  const int NB = (N + 255)/256;       // 196 (<=256 required by scan_top)
  const int EB = (E + 255)/256;

  // zero deg + bcnt + boff in one memset (contiguous carves)
  size_t degSpan = (((size_t)N*4 + 255) & ~size_t(255)) + 512;
  hipMemsetAsync(deg, 0, degSpan, stream);
  // CSR by dst (self-loop first) + weight packing + degree buckets
  k_count_pack<<<EB,256,0,stream>>>(ei, deg, E, W1, W2, Wp1, Wm1, Wm2,
                                    Wpk1, Wpk2, Wpkp, Apke);
  k_scan_part <<<NB,256,0,stream>>>(deg, bsum, N);
  k_scan_top  <<<1 ,256,0,stream>>>(bsum, bpre, NB);
  k_scan_final<<<NB,256,0,stream>>>(deg, bpre, row_start, csr_src, cursor, bcnt, N, E + N);
  k_bucket_scan<<<1,64,0,stream>>>(bcnt, boff);
  k_bucket_scatter<<<NB,256,0,stream>>>(deg, boff, order, N);
  k_fill_edges<<<EB,256,0,stream>>>(ei, cursor, csr_src, E);

  const int GB = (N + 31)/32;
  const int AB = 8 * ((N + 63)/64);   // head-split agg grid (head = blockIdx & 7)
  // GAT layer 1:  x(fp32) -> Hh -> Xh
  k_gemm_mfma<128,true ><<<GB,256,0,stream>>>(x,  Wpk1, as1, ad1, Hh, AS, AD, N);
  k_gat_agg<<<AB,256,0,stream>>>(row_start, csr_src, order, Hh, AS, AD, b1, Xh, N);
  // GAT layer 2:  Xh -> Hh -> Xh
  k_gemm_mfma<256,false><<<GB,256,0,stream>>>(Xh, Wpk2, as2, ad2, Hh, AS, AD, N);
  k_gat_agg<<<AB,256,0,stream>>>(row_start, csr_src, order, Hh, AS, AD, b2, Xh, N);

  // predictor decomposition
  k_node_proj_mfma<<<(N+63)/64,256,0,stream>>>(Xh, Wpkp, P, N);
  k_edge_mfma<<<(E+255)/256,256,0,stream>>>(ei, ea, Apke, bm1, bm2, bp1,
                                            P, Wp2, bp2, (float*)d_out, E);
}

// Round 11
// 371.640 us; speedup vs baseline: 1.9068x; 1.9068x over previous
//
#include <hip/hip_runtime.h>
#include <hip/hip_fp16.h>

typedef __half h16;
static __device__ __forceinline__ h16  f2h(float v){ return __float2half(v); }

typedef _Float16 f16x8 __attribute__((ext_vector_type(8)));
typedef float    f32x4 __attribute__((ext_vector_type(4)));

// pack two floats -> h2 in a uint (RNE)
static __device__ __forceinline__ unsigned pk2(float a, float b){
  return ((unsigned)__half_as_ushort(__float2half(b)) << 16) |
          (unsigned)__half_as_ushort(__float2half(a));
}

#define HEADS 8
#define HID 32
#define NHID 256

// ---------------- CSR build + weight packing ----------------
// fused: edge-degree count (idx<E) + all MFMA weight fragment packing (idx<117760)
__global__ void k_count_pack(const int* __restrict__ ei, int* __restrict__ deg, int E,
                             const float* __restrict__ W1, const float* __restrict__ W2,
                             const float* __restrict__ Wp1, const float* __restrict__ Wm1,
                             const float* __restrict__ Wm2,
                             _Float16* __restrict__ Wpk1, _Float16* __restrict__ Wpk2,
                             _Float16* __restrict__ Wpkp, _Float16* __restrict__ Apke){
  int idx = blockIdx.x*256 + threadIdx.x;
  if (idx < E) atomicAdd(&deg[ei[E + idx]], 1);   // dst = edge_index[1]
  if (idx < 32768){
    int i = idx;
    int j=i&7, lane=(i>>3)&63, ct=(i>>9)&15, kc=i>>13;
    int k = kc*32 + ((lane>>4)<<3) + j, c = (ct<<4) + (lane&15);
    Wpk1[i] = (_Float16)W1[(size_t)k*NHID + c];
  } else if (idx < 98304){
    int i = idx - 32768;
    int j=i&7, lane=(i>>3)&63, ct=(i>>9)&15, kc=i>>13;
    int k = kc*32 + ((lane>>4)<<3) + j, c = (ct<<4) + (lane&15);
    Wpk2[i] = (_Float16)W2[(size_t)k*NHID + c];
  } else if (idx < 114688){
    int i = idx - 98304;
    int j=i&7, lane=(i>>3)&63, ct=(i>>9)&3, kc=i>>11;
    int k = kc*32 + ((lane>>4)<<3) + j, c = (ct<<4) + (lane&15);
    float v = (c < 32) ? Wp1[(size_t)k*32 + c] : Wp1[(size_t)(256+k)*32 + (c-32)];
    Wpkp[i] = (_Float16)v;
  } else if (idx < 117760){
    int i = idx - 114688;               // < 3072
    int j=i&7, lane=(i>>3)&63, mt=(i>>9)&1, layer=i>>10;
    int k = ((lane>>4)<<3) + j, c = mt*16 + (lane&15);
    const float* W = (layer==0) ? Wm1 : (layer==1) ? Wm2 : (Wp1 + 512*32);
    Apke[i] = (_Float16)W[k*32 + c];
  }
}
__global__ void k_scan_part(const int* __restrict__ deg, int* __restrict__ bsum, int N){
  __shared__ int s[256];
  int t = threadIdx.x, i = blockIdx.x*256 + t;
  s[t] = (i < N) ? deg[i] + 1 : 0;
  __syncthreads();
  for (int off = 128; off > 0; off >>= 1){
    if (t < off) s[t] += s[t+off];
    __syncthreads();
  }
  if (t == 0) bsum[blockIdx.x] = s[0];
}
__global__ void k_scan_top(const int* __restrict__ bsum, int* __restrict__ bpre, int nb){
  __shared__ int s[256];
  int t = threadIdx.x;
  int v = (t < nb) ? bsum[t] : 0;
  s[t] = v; __syncthreads();
  for (int off = 1; off < 256; off <<= 1){
    int x = (t >= off) ? s[t-off] : 0;
    __syncthreads();
    s[t] += x;
    __syncthreads();
  }
  if (t < nb) bpre[t] = s[t] - v;             // exclusive block prefix
}
// fills row_start + self-loop entry + cursor + degree-bucket counts (LDS histogram:
// round-10 lesson — 50k global atomics on 32 addresses serialized to 171 us)
__global__ void k_scan_final(const int* __restrict__ deg, const int* __restrict__ bpre,
                             int* __restrict__ row_start, int* __restrict__ csr_src,
                             int* __restrict__ cursor, int* __restrict__ bcnt,
                             int N, int total){
  __shared__ int s[256];
  __shared__ int hist[32];
  int t = threadIdx.x, i = blockIdx.x*256 + t;
  if (t < 32) hist[t] = 0;
  int v = (i < N) ? deg[i] + 1 : 0;
  s[t] = v; __syncthreads();
  for (int off = 1; off < 256; off <<= 1){
    int x = (t >= off) ? s[t-off] : 0;
    __syncthreads();
    s[t] += x;
    __syncthreads();
  }
  if (i < N){
    int p = bpre[blockIdx.x] + s[t] - v;
    row_start[i] = p;
    csr_src[p] = i;          // self-loop first
    cursor[i] = p + 1;
    atomicAdd(&hist[min(v, 31)], 1);
  }
  if (i == 0) row_start[N] = total;
  __syncthreads();
  if (t < 32 && hist[t] > 0) atomicAdd(&bcnt[t], hist[t]);
}
__global__ void k_bucket_scan(const int* __restrict__ bcnt, int* __restrict__ boff){
  if (threadIdx.x == 0){
    int run = 0;
    for (int b = 0; b < 32; b++){ boff[b] = run; run += bcnt[b]; }
  }
}
// two-phase scatter: block-local histogram -> one base-claim atomic per (block,bucket)
// -> LDS-rank scatter. Replaces 50k contended global atomics with ~6k spread ones.
__global__ void k_bucket_scatter(const int* __restrict__ deg, int* __restrict__ boff,
                                 int* __restrict__ order, int N){
  __shared__ int hist[32], base[32];
  int t = threadIdx.x, n = blockIdx.x*256 + t;
  if (t < 32) hist[t] = 0;
  __syncthreads();
  int b = 0;
  if (n < N){
    b = min(deg[n] + 1, 31);
    atomicAdd(&hist[b], 1);
  }
  __syncthreads();
  if (t < 32) base[t] = (hist[t] > 0) ? atomicAdd(&boff[t], hist[t]) : 0;
  __syncthreads();
  if (t < 32) hist[t] = 0;
  __syncthreads();
  if (n < N){
    int r = atomicAdd(&hist[b], 1);
    order[base[b] + r] = n;
  }
}
__global__ void k_fill_edges(const int* __restrict__ ei, int* __restrict__ cursor,
                             int* __restrict__ csr_src, int E){
  int e = blockIdx.x*256 + threadIdx.x;
  if (e < E){
    int src = ei[e], dst = ei[E + e];
    int p = atomicAdd(&cursor[dst], 1);
    csr_src[p] = src;
  }
}

// ---------------- MFMA GEMM (X@W) + alpha; H/AS/AD written HEAD-MAJOR ----------------
// H: [8][N][32] fp16; AS/AD: [8][N] fp32. INF32=false input X is head-major [8][N][32] h16.
template<int K, bool INF32>
__global__ __launch_bounds__(256) void k_gemm_mfma(
    const void* __restrict__ xin, const _Float16* __restrict__ Wpk,
    const float* __restrict__ asrc, const float* __restrict__ adst,
    h16* __restrict__ H, float* __restrict__ AS, float* __restrict__ AD, int N)
{
  __shared__ __align__(16) _Float16 xs[32][K+8];   // +8 halves pad
  const int t = threadIdx.x;
  const int n0 = blockIdx.x * 32;
  constexpr int K8 = K/8;
  for (int i = t; i < 32*K8; i += 256){
    int r = i / K8, c8 = (i - r*K8)*8;
    if (INF32){
      _Float16 v[8];
      if (n0+r < N){
        const float4* gp = (const float4*)((const float*)xin + (size_t)(n0+r)*K + c8);
        float4 u0 = gp[0], u1 = gp[1];
        v[0]=(_Float16)u0.x; v[1]=(_Float16)u0.y; v[2]=(_Float16)u0.z; v[3]=(_Float16)u0.w;
        v[4]=(_Float16)u1.x; v[5]=(_Float16)u1.y; v[6]=(_Float16)u1.z; v[7]=(_Float16)u1.w;
      } else {
        for (int j=0;j<8;j++) v[j]=(_Float16)0.f;
      }
      *(f16x8*)&xs[r][c8] = *(f16x8*)v;
    } else {
      uint4 u = make_uint4(0,0,0,0);
      if (n0+r < N)
        u = *(const uint4*)((const h16*)xin + ((size_t)(c8>>5)*N + (n0+r))*32 + (c8&31));
      *(uint4*)&xs[r][c8] = u;
    }
  }
  __syncthreads();

  const int wid = t >> 6, lane = t & 63;
  const int mcol = lane & 15, kq = lane >> 4;
  f32x4 acc[4][2];
#pragma unroll
  for (int ct = 0; ct < 4; ct++)
#pragma unroll
    for (int rt = 0; rt < 2; rt++) acc[ct][rt] = (f32x4){0.f,0.f,0.f,0.f};

  for (int kc = 0; kc < K/32; kc++){
    f16x8 a0 = *(const f16x8*)&xs[mcol     ][kc*32 + kq*8];
    f16x8 a1 = *(const f16x8*)&xs[16 + mcol][kc*32 + kq*8];
#pragma unroll
    for (int ct = 0; ct < 4; ct++){
      f16x8 b = *(const f16x8*)&Wpk[(((size_t)kc*16 + wid*4 + ct)*64 + lane)*8];
      acc[ct][0] = __builtin_amdgcn_mfma_f32_16x16x32_f16(a0, b, acc[ct][0], 0,0,0);
      acc[ct][1] = __builtin_amdgcn_mfma_f32_16x16x32_f16(a1, b, acc[ct][1], 0,0,0);
    }
  }

  float av[4], dv[4];
#pragma unroll
  for (int ct = 0; ct < 4; ct++){
    int c = wid*64 + ct*16 + mcol;
    av[ct] = asrc[c]; dv[ct] = adst[c];
  }
#pragma unroll
  for (int rt = 0; rt < 2; rt++){
#pragma unroll
    for (int r = 0; r < 4; r++){
      const int n = n0 + rt*16 + kq*4 + r;
      const bool ok = n < N;
      if (ok){
#pragma unroll
        for (int ct = 0; ct < 4; ct++){
          H[((size_t)(wid*2 + (ct>>1))*N + n)*32 + (ct&1)*16 + mcol] = f2h(acc[ct][rt][r]);
        }
      }
      float s1a = acc[0][rt][r]*av[0] + acc[1][rt][r]*av[1];
      float s2a = acc[0][rt][r]*dv[0] + acc[1][rt][r]*dv[1];
      float s1b = acc[2][rt][r]*av[2] + acc[3][rt][r]*av[3];
      float s2b = acc[2][rt][r]*dv[2] + acc[3][rt][r]*dv[3];
#pragma unroll
      for (int off = 1; off < 16; off <<= 1){
        s1a += __shfl_xor(s1a, off); s2a += __shfl_xor(s2a, off);
        s1b += __shfl_xor(s1b, off); s2b += __shfl_xor(s2b, off);
      }
      if (mcol == 0 && ok){
        AS[(size_t)(wid*2    )*N + n] = s1a;  AD[(size_t)(wid*2    )*N + n] = s2a;
        AS[(size_t)(wid*2 + 1)*N + n] = s1b;  AD[(size_t)(wid*2 + 1)*N + n] = s2b;
      }
    }
  }
}

// ------------- GAT aggregation: 4-lane group per (node, head), head-split + XCD swizzle ----
// Nodes taken in degree-bucketed order -> waves have near-uniform degree (minimal masked
// iterations). Unroll-4: 4 gather chains in flight, 2 FMA accumulation chains.
__global__ __launch_bounds__(256) void k_gat_agg(
    const int* __restrict__ row_start, const int* __restrict__ csr_src,
    const int* __restrict__ order,
    const h16* __restrict__ H, const float* __restrict__ AS, const float* __restrict__ AD,
    const float* __restrict__ bias, h16* __restrict__ Xout, int N)
{
  const int head = blockIdx.x & 7;
  const int t = threadIdx.x;
  const int wv = t >> 6, lane = t & 63;
  const int g = lane >> 2, cl = lane & 3;
  const int ni = (blockIdx.x >> 3)*64 + wv*16 + g;
  if (ni >= N) return;
  const int n = order[ni];
  const int rs = row_start[n];
  const int deg = row_start[n+1] - rs;         // >=1 (self-loop)
  const h16* __restrict__ Hh = H + (size_t)head*N*32;
  const float* __restrict__ ASh = AS + (size_t)head*N;
  const float adv = AD[(size_t)head*N + n];
  const int co = cl*8;

  float accA[8] = {0,0,0,0,0,0,0,0};
  float accB[8] = {0,0,0,0,0,0,0,0};
  float dA = 0.f, dB = 0.f;
  int k = 0;
  for (; k + 4 <= deg; k += 4){
    const int s0 = csr_src[rs + k    ];
    const int s1 = csr_src[rs + k + 1];
    const int s2 = csr_src[rs + k + 2];
    const int s3 = csr_src[rs + k + 3];
    const float v0 = ASh[s0] + adv;
    const float v1 = ASh[s1] + adv;
    const float v2 = ASh[s2] + adv;
    const float v3 = ASh[s3] + adv;
    union { uint4 u; __half2 h[4]; } h0, h1, h2, h3;
    h0.u = *(const uint4*)(Hh + (size_t)s0*32 + co);
    h1.u = *(const uint4*)(Hh + (size_t)s1*32 + co);
    h2.u = *(const uint4*)(Hh + (size_t)s2*32 + co);
    h3.u = *(const uint4*)(Hh + (size_t)s3*32 + co);
    const float w0 = __expf(v0 > 0.f ? v0 : 0.2f*v0);
    const float w1 = __expf(v1 > 0.f ? v1 : 0.2f*v1);
    const float w2 = __expf(v2 > 0.f ? v2 : 0.2f*v2);
    const float w3 = __expf(v3 > 0.f ? v3 : 0.2f*v3);
    dA += w0 + w2; dB += w1 + w3;
#pragma unroll
    for (int i = 0; i < 4; i++){
      float2 f0 = __half22float2(h0.h[i]);
      float2 f1 = __half22float2(h1.h[i]);
      float2 f2 = __half22float2(h2.h[i]);
      float2 f3 = __half22float2(h3.h[i]);
      accA[2*i]   = fmaf(w0, f0.x, fmaf(w2, f2.x, accA[2*i]));
      accA[2*i+1] = fmaf(w0, f0.y, fmaf(w2, f2.y, accA[2*i+1]));
      accB[2*i]   = fmaf(w1, f1.x, fmaf(w3, f3.x, accB[2*i]));
      accB[2*i+1] = fmaf(w1, f1.y, fmaf(w3, f3.y, accB[2*i+1]));
    }
  }
  for (; k < deg; k++){
    const int sa = csr_src[rs + k];
    const float va = ASh[sa] + adv;
    union { uint4 u; __half2 h[4]; } ha;
    ha.u = *(const uint4*)(Hh + (size_t)sa*32 + co);
    const float wa = __expf(va > 0.f ? va : 0.2f*va);
    dA += wa;
#pragma unroll
    for (int i = 0; i < 4; i++){
      float2 fa = __half22float2(ha.h[i]);
      accA[2*i]   = fmaf(wa, fa.x, accA[2*i]);
      accA[2*i+1] = fmaf(wa, fa.y, accA[2*i+1]);
    }
  }
  const float inv_d = 1.f / (dA + dB);
  const float4 b0 = *(const float4*)(bias + head*32 + co);
  const float4 b1 = *(const float4*)(bias + head*32 + co + 4);
  uint4 o;
  o.x = pk2(fmaxf(fmaf(accA[0]+accB[0], inv_d, b0.x), 0.f),
            fmaxf(fmaf(accA[1]+accB[1], inv_d, b0.y), 0.f));
  o.y = pk2(fmaxf(fmaf(accA[2]+accB[2], inv_d, b0.z), 0.f),
            fmaxf(fmaf(accA[3]+accB[3], inv_d, b0.w), 0.f));
  o.z = pk2(fmaxf(fmaf(accA[4]+accB[4], inv_d, b1.x), 0.f),
            fmaxf(fmaf(accA[5]+accB[5], inv_d, b1.y), 0.f));
  o.w = pk2(fmaxf(fmaf(accA[6]+accB[6], inv_d, b1.z), 0.f),
            fmaxf(fmaf(accA[7]+accB[7], inv_d, b1.w), 0.f));
  *(uint4*)(Xout + ((size_t)head*N + n)*32 + co) = o;
}

// ------------- MFMA node projections: P[N][64] = X2(head-major) @ Wcat -------------
__global__ __launch_bounds__(256) void k_node_proj_mfma(
    const h16* __restrict__ X2, const _Float16* __restrict__ Wpk,
    h16* __restrict__ P, int N)
{
  __shared__ __align__(16) _Float16 xs[64][NHID+8];
  const int t = threadIdx.x;
  const int n0 = blockIdx.x * 64;
  for (int i = t; i < 64*32; i += 256){
    int r = i >> 5, c8 = (i & 31)*8;
    uint4 u = make_uint4(0,0,0,0);
    if (n0+r < N)
      u = *(const uint4*)(X2 + ((size_t)(c8>>5)*N + (n0+r))*32 + (c8&31));
    *(uint4*)&xs[r][c8] = u;
  }
  __syncthreads();

  const int wid = t >> 6, lane = t & 63;
  const int mcol = lane & 15, kq = lane >> 4;
  f32x4 acc[4];
#pragma unroll
  for (int rt = 0; rt < 4; rt++) acc[rt] = (f32x4){0.f,0.f,0.f,0.f};

  for (int kc = 0; kc < 8; kc++){
    f16x8 b = *(const f16x8*)&Wpk[(((size_t)kc*4 + wid)*64 + lane)*8];
#pragma unroll
    for (int rt = 0; rt < 4; rt++){
      f16x8 a = *(const f16x8*)&xs[rt*16 + mcol][kc*32 + kq*8];
      acc[rt] = __builtin_amdgcn_mfma_f32_16x16x32_f16(a, b, acc[rt], 0,0,0);
    }
  }

  const int c = wid*16 + mcol;
#pragma unroll
  for (int rt = 0; rt < 4; rt++){
#pragma unroll
    for (int r = 0; r < 4; r++){
      const int n = n0 + rt*16 + kq*4 + r;
      if (n < N) P[(size_t)n*64 + c] = f2h(acc[rt][r]);
    }
  }
}

// ------------- edge tail, all-register MFMA: zero LDS, zero barriers -------------
__global__ __launch_bounds__(256) void k_edge_mfma(
    const int* __restrict__ ei, const float* __restrict__ ea,
    const _Float16* __restrict__ Apk,
    const float* __restrict__ bm1, const float* __restrict__ bm2,
    const float* __restrict__ bp1,
    const h16* __restrict__ P, const float* __restrict__ Wp2,
    const float* __restrict__ bp2,
    float* __restrict__ out, int E)
{
  union U8 { f16x8 v; unsigned u[4]; };
  const int t = threadIdx.x;
  const int wid = t >> 6, lane = t & 63;
  const int mcol = lane & 15, kq = lane >> 4;
  const int e0w = blockIdx.x*256 + wid*64;

  float4 bv1[2], bv2[2], bv3[2], wv4[2];
#pragma unroll
  for (int mt = 0; mt < 2; mt++){
    bv1[mt] = *(const float4*)(bm1 + mt*16 + kq*4);
    bv2[mt] = *(const float4*)(bm2 + mt*16 + kq*4);
    bv3[mt] = *(const float4*)(bp1 + mt*16 + kq*4);
    wv4[mt] = *(const float4*)(Wp2 + mt*16 + kq*4);
  }
  const float bp2v = bp2[0];

  f32x4 acc[2][4];
  unsigned pkLo[2][4], pkHi[2][4];
  const int l1 = (kq & 1)*32 + mcol;
  const int l2 = l1 + 16;
  const int mt_hi = kq >> 1;

  // ---- layer 1: B from global ea ----
#pragma unroll
  for (int nt = 0; nt < 4; nt++){
    const int e = e0w + nt*16 + mcol;
    U8 b;
    if (e < E){
      const float4* gp = (const float4*)(ea + (size_t)e*32 + kq*8);
      float4 u0 = gp[0], u1 = gp[1];
      b.u[0] = pk2(u0.x, u0.y); b.u[1] = pk2(u0.z, u0.w);
      b.u[2] = pk2(u1.x, u1.y); b.u[3] = pk2(u1.z, u1.w);
    } else {
      b.u[0]=b.u[1]=b.u[2]=b.u[3]=0u;
    }
#pragma unroll
    for (int mt = 0; mt < 2; mt++){
      f16x8 a = *(const f16x8*)&Apk[((0*2+mt)*64 + lane)*8];
      acc[mt][nt] = (f32x4){bv1[mt].x, bv1[mt].y, bv1[mt].z, bv1[mt].w};
      acc[mt][nt] = __builtin_amdgcn_mfma_f32_16x16x32_f16(a, b.v, acc[mt][nt], 0,0,0);
    }
  }

  // ---- transitions + layers 2,3 ----
#pragma unroll
  for (int layer = 1; layer < 3; layer++){
#pragma unroll
    for (int mt = 0; mt < 2; mt++)
#pragma unroll
      for (int nt = 0; nt < 4; nt++){
        float r0 = fmaxf(acc[mt][nt][0], 0.f), r1 = fmaxf(acc[mt][nt][1], 0.f);
        float r2 = fmaxf(acc[mt][nt][2], 0.f), r3 = fmaxf(acc[mt][nt][3], 0.f);
        pkLo[mt][nt] = pk2(r0, r1);
        pkHi[mt][nt] = pk2(r2, r3);
      }
#pragma unroll
    for (int nt = 0; nt < 4; nt++){
      unsigned a0 = (unsigned)__shfl((int)pkLo[0][nt], l1);
      unsigned a1 = (unsigned)__shfl((int)pkHi[0][nt], l1);
      unsigned a2 = (unsigned)__shfl((int)pkLo[0][nt], l2);
      unsigned a3 = (unsigned)__shfl((int)pkHi[0][nt], l2);
      unsigned c0 = (unsigned)__shfl((int)pkLo[1][nt], l1);
      unsigned c1 = (unsigned)__shfl((int)pkHi[1][nt], l1);
      unsigned c2 = (unsigned)__shfl((int)pkLo[1][nt], l2);
      unsigned c3 = (unsigned)__shfl((int)pkHi[1][nt], l2);
      U8 b;
      b.u[0] = mt_hi ? c0 : a0; b.u[1] = mt_hi ? c1 : a1;
      b.u[2] = mt_hi ? c2 : a2; b.u[3] = mt_hi ? c3 : a3;
      const float4 bv = (layer==1) ? bv2[0] : bv3[0];
      const float4 bw = (layer==1) ? bv2[1] : bv3[1];
      f16x8 A0 = *(const f16x8*)&Apk[((layer*2+0)*64 + lane)*8];
      f16x8 A1 = *(const f16x8*)&Apk[((layer*2+1)*64 + lane)*8];
      f32x4 n0 = (f32x4){bv.x, bv.y, bv.z, bv.w};
      f32x4 n1 = (f32x4){bw.x, bw.y, bw.z, bw.w};
      n0 = __builtin_amdgcn_mfma_f32_16x16x32_f16(A0, b.v, n0, 0,0,0);
      n1 = __builtin_amdgcn_mfma_f32_16x16x32_f16(A1, b.v, n1, 0,0,0);
      acc[0][nt] = n0;
      acc[1][nt] = n1;
    }
  }

  // ---- tail: p = sum_c relu(P1[row][c]+P2[col][c]+EC[e][c]) * Wp2[c] ----
#pragma unroll
  for (int nt = 0; nt < 4; nt++){
    const int e = e0w + nt*16 + mcol;
    const bool ok = e < E;
    const int row  = ok ? ei[e]     : 0;
    const int colv = ok ? ei[E + e] : 0;
    float p = 0.f;
#pragma unroll
    for (int mt = 0; mt < 2; mt++){
      const __half2* p1p = (const __half2*)(P + (size_t)row*64      + mt*16 + kq*4);
      const __half2* p2p = (const __half2*)(P + (size_t)colv*64 + 32 + mt*16 + kq*4);
      __half2 x0 = p1p[0], x1 = p1p[1], y0 = p2p[0], y1 = p2p[1];
      float v0 = __half2float(x0.x) + __half2float(y0.x) + acc[mt][nt][0];
      float v1 = __half2float(x0.y) + __half2float(y0.y) + acc[mt][nt][1];
      float v2 = __half2float(x1.x) + __half2float(y1.x) + acc[mt][nt][2];
      float v3 = __half2float(x1.y) + __half2float(y1.y) + acc[mt][nt][3];
      v0 = fmaxf(v0,0.f); v1 = fmaxf(v1,0.f); v2 = fmaxf(v2,0.f); v3 = fmaxf(v3,0.f);
      p += v0*wv4[mt].x + v1*wv4[mt].y + v2*wv4[mt].z + v3*wv4[mt].w;
    }
    p += __shfl_xor(p, 16);
    p += __shfl_xor(p, 32);
    if (kq == 0 && ok) out[e] = p + bp2v;
  }
}

extern "C" void kernel_launch(void* const* d_in, const int* in_sizes, int n_in,
                              void* d_out, int out_size, void* d_ws, size_t ws_size,
                              hipStream_t stream)
{
  const float* x   = (const float*)d_in[0];
  const int*   ei  = (const int*)  d_in[1];
  const float* ea  = (const float*)d_in[2];
  const float* W1  = (const float*)d_in[3];
  const float* as1 = (const float*)d_in[4];
  const float* ad1 = (const float*)d_in[5];
  const float* b1  = (const float*)d_in[6];
  const float* W2  = (const float*)d_in[7];
  const float* as2 = (const float*)d_in[8];
  const float* ad2 = (const float*)d_in[9];
  const float* b2  = (const float*)d_in[10];
  const float* Wm1 = (const float*)d_in[11];
  const float* bm1 = (const float*)d_in[12];
  const float* Wm2 = (const float*)d_in[13];
  const float* bm2 = (const float*)d_in[14];
  const float* Wp1 = (const float*)d_in[15];
  const float* bp1 = (const float*)d_in[16];
  const float* Wp2 = (const float*)d_in[17];
  const float* bp2 = (const float*)d_in[18];

  const int N = in_sizes[0] / 128;    // 50000
  const int E = in_sizes[1] / 2;      // 400000

  char* p = (char*)d_ws;
  auto carve = [&](size_t bytes) -> void* {
    void* q = (void*)p; p += (bytes + 255) & ~size_t(255); return q;
  };
  h16* Hh   = (h16*)carve((size_t)N*NHID*2);      // 25.6 MB [8][N][32]
  h16* Xh   = (h16*)carve((size_t)N*NHID*2);      // 25.6 MB [8][N][32] (X1 then X2)
  float* AS = (float*)carve((size_t)N*HEADS*4);   // 1.6 MB [8][N]
  float* AD = (float*)carve((size_t)N*HEADS*4);   // 1.6 MB [8][N]
  h16* P    = (h16*)carve((size_t)N*64*2);        // 6.4 MB  [N][64] = [P1|P2]
  int* deg       = (int*)carve((size_t)N*4);      // \  contiguous: one memset covers
  int* bcnt      = (int*)carve(128);              //  | deg + bcnt + boff
  int* boff      = (int*)carve(128);              // /
  int* cursor    = (int*)carve((size_t)N*4);
  int* row_start = (int*)carve((size_t)(N+1)*4);
  int* csr_src   = (int*)carve((size_t)(E+N)*4);
  int* order     = (int*)carve((size_t)N*4);
  int* bsum      = (int*)carve(1024);
  int* bpre      = (int*)carve(1024);
  _Float16* Wpk1 = (_Float16*)carve((size_t)128*NHID*2);  // 64 KB
  _Float16* Wpk2 = (_Float16*)carve((size_t)256*NHID*2);  // 128 KB
  _Float16* Wpkp = (_Float16*)carve((size_t)256*64*2);    // 32 KB
  _Float16* Apke = (_Float16*)carve((size_t)3072*2);      // 6 KB

  const int NB = (N + 255)/256;       // 196 (<=256 required by scan_top)
  const int EB = (E + 255)/256;

  // zero deg + bcnt + boff in one memset (contiguous carves)
  size_t degSpan = (((size_t)N*4 + 255) & ~size_t(255)) + 512;
  hipMemsetAsync(deg, 0, degSpan, stream);
  // CSR by dst (self-loop first) + weight packing + degree buckets
  k_count_pack<<<EB,256,0,stream>>>(ei, deg, E, W1, W2, Wp1, Wm1, Wm2,
                                    Wpk1, Wpk2, Wpkp, Apke);
  k_scan_part <<<NB,256,0,stream>>>(deg, bsum, N);
  k_scan_top  <<<1 ,256,0,stream>>>(bsum, bpre, NB);
  k_scan_final<<<NB,256,0,stream>>>(deg, bpre, row_start, csr_src, cursor, bcnt, N, E + N);
  k_bucket_scan<<<1,64,0,stream>>>(bcnt, boff);
  k_bucket_scatter<<<NB,256,0,stream>>>(deg, boff, order, N);
  k_fill_edges<<<EB,256,0,stream>>>(ei, cursor, csr_src, E);

  const int GB = (N + 31)/32;
  const int AB = 8 * ((N + 63)/64);   // head-split agg grid (head = blockIdx & 7)
  // GAT layer 1:  x(fp32) -> Hh -> Xh
  k_gemm_mfma<128,true ><<<GB,256,0,stream>>>(x,  Wpk1, as1, ad1, Hh, AS, AD, N);
  k_gat_agg<<<AB,256,0,stream>>>(row_start, csr_src, order, Hh, AS, AD, b1, Xh, N);
  // GAT layer 2:  Xh -> Hh -> Xh
  k_gemm_mfma<256,false><<<GB,256,0,stream>>>(Xh, Wpk2, as2, ad2, Hh, AS, AD, N);
  k_gat_agg<<<AB,256,0,stream>>>(row_start, csr_src, order, Hh, AS, AD, b2, Xh, N);

  // predictor decomposition
  k_node_proj_mfma<<<(N+63)/64,256,0,stream>>>(Xh, Wpkp, P, N);
  k_edge_mfma<<<(E+255)/256,256,0,stream>>>(ei, ea, Apke, bm1, bm2, bp1,
                                            P, Wp2, bp2, (float*)d_out, E);
}